// Round 4
// baseline (124.395 us; speedup 1.0000x reference)
//
#include <hip/hip_runtime.h>
#include <math.h>

// DirectionalContrastiveLoss — N=8, C=192, H=W=112, T=0.1
//
// R9 (resubmit after infra failure; source audited for OOB/hang — none found).
//  - tile 14x14 px (+halo = 16x16 = 256 slots = NT2): grid 512 blocks,
//    exactly 2 blocks/CU (cross-block overlap at every barrier; R8's 1/CU
//    exposed all 12 barrier drains).
//  - XCD swizzle: 1-D grid, n = bid&7 -> each XCD owns one image; per-chunk
//    slab 401KB is L2-resident so halo re-reads never hit HBM.
//  - vertical QUAD blocking: 4 px/thread, streamed 6x3 window = 36 b128/chunk
//    for 4 px (R8 pair: 24 for 2). 56 quad-threads = ONE issuing wave/half
//    (R8: 98 -> 2 ragged waves). LDS-read pipe 11.5 -> 8.6 us/CU.
//  - shared vertical d=0 dots (S01/S12/S23): 29 v2f accs (58 VGPR).
//  - tile rows padded to 17 v4f: quad's 4-row lane stride would alias 4-way
//    on 32 banks unpadded; pad makes it 2-way (free).
//  - epilogue split: half0 owns px0/px1, half1 owns px2/px3; partials
//    exchanged via LDS.

namespace {
constexpr int N_ = 8, C_ = 192, H_ = 112, W_ = 112;
constexpr int HW = H_ * W_;
constexpr int TH = 14, WS = 14;        // pixel tile
constexpr int TROWS = 16, TCOLS = 16;  // +halo
constexpr int TPAD = 17;               // padded row stride (v4f units)
constexpr int TILE_E = 256;            // staging slots = NT2
constexpr int NT2 = 256;               // threads per channel-half
constexpr int NT = 2 * NT2;            // 512
constexpr int NQT = 4 * WS;            // 56 quad threads per half
constexpr int CHALF = C_ / 2;          // 96
constexpr int KCH = 8;                 // channels per chunk per half
constexpr int GRP = KCH / 4;           // 2 float4 groups
constexpr int NCHUNK = CHALF / KCH;    // 12
constexpr int NBLK = 8 * 8 * 8;        // 512
constexpr float INV_T = 10.0f;
constexpr double TOTAL = (double)N_ * N_ * H_ * W_;  // 802816
}

typedef float v2f __attribute__((ext_vector_type(2)));
typedef float v4f __attribute__((ext_vector_type(4)));

__device__ __forceinline__ void pk(v2f& a, v2f x, v2f y) {
    asm("v_pk_fma_f32 %0, %1, %2, %0" : "+v"(a) : "v"(x), "v"(y));
}
__device__ __forceinline__ void pk4(v2f& a, v4f x, v4f y) {
    pk(a, x.lo, y.lo); pk(a, x.hi, y.hi);
}

__device__ __forceinline__ float sel3(int d, float a, float b, float c) {
    float r = (d < 0) ? a : b;
    return (d > 0) ? c : r;
}

extern "C" __global__ void __launch_bounds__(NT, 4)
dcl_main(const float* __restrict__ feat,
         const int* __restrict__ labels,
         const int* __restrict__ dirs,
         double* __restrict__ partial, int use_partial)
{
    __shared__ v4f   tiles[2][2][GRP][16 * TPAD];  // 34.8 KB
    __shared__ float ssp[2][TILE_E];               // 2 KB
    __shared__ float ssbuf[TILE_E];                // 1 KB
    __shared__ float exA[NQT][17];                 // half1's px0/px1 partials
    __shared__ float exB[NQT][17];                 // half0's px2/px3 partials
    __shared__ float red[NT / 64];

    const int bid = blockIdx.x;
    const int n   = bid & 7;            // XCD swizzle: image n -> XCD n
    const int tt  = bid >> 3;           // 0..63 tile index
    const int tyb = tt >> 3;            // 0..7
    const int txb = tt & 7;             // 0..7
    const int gy0 = tyb * TH;
    const int gx0 = txb * WS;

    const int tid  = threadIdx.x;
    const int half = tid >> 8;
    const int t8   = tid & (NT2 - 1);

    // ---- staging slot (exactly one per thread)
    const int sr = t8 >> 4, sc = t8 & 15;
    const int spad = sr * TPAD + sc;
    const int gofs = min(max(gy0 + sr - 1, 0), H_ - 1) * W_
                   + min(max(gx0 + sc - 1, 0), W_ - 1);

    // ---- quad mapping
    const bool is_q = (t8 < NQT);
    const int qy = t8 / WS;              // 0..3
    const int tx = t8 - qy * WS;         // 0..13
    const int b  = (qy == 3) ? 10 : 4 * qy;   // first image row of quad
    const int top = b * TPAD + tx;       // padded window base
    const int gj  = gx0 + tx;

    const float* __restrict__ plane =
        feat + ((size_t)n * C_ + (size_t)half * CHALF) * HW;

    float ss0 = 0.0f;

    // ---- prologue: stage chunk 0 into buffer 0
    {
        #pragma unroll
        for (int g = 0; g < GRP; ++g) {
            float a0 = plane[(size_t)(4 * g + 0) * HW + gofs];
            float a1 = plane[(size_t)(4 * g + 1) * HW + gofs];
            float a2 = plane[(size_t)(4 * g + 2) * HW + gofs];
            float a3 = plane[(size_t)(4 * g + 3) * HW + gofs];
            ss0 += a0 * a0 + a1 * a1 + a2 * a2 + a3 * a3;
            v4f v = {a0, a1, a2, a3};
            tiles[half][0][g][spad] = v;
        }
    }
    __syncthreads();

    // accumulators (29 live): p?[1],p?[6] unused where shared
    v2f p0[8], p1[8], p2[8], p3[8], s01, s12, s23;
    {
        const v2f z = {0.f, 0.f};
        #pragma unroll
        for (int d = 0; d < 8; ++d) { p0[d]=z; p1[d]=z; p2[d]=z; p3[d]=z; }
        s01 = z; s12 = z; s23 = z;
    }

    // ---- chunk loop
    for (int t = 0; t < NCHUNK; ++t) {
        float pv[KCH];
        const bool more = (t + 1 < NCHUNK);
        if (more) {
            const float* p = plane + (size_t)(t + 1) * KCH * HW;
            #pragma unroll
            for (int k = 0; k < KCH; ++k) pv[k] = p[(size_t)k * HW + gofs];
        }

        if (is_q) {
            #pragma unroll
            for (int g = 0; g < GRP; ++g) {
                const v4f* __restrict__ cp = tiles[half][t & 1][g];
                v4f A0 = cp[top +  0], B0 = cp[top +  1], C0 = cp[top +  2];
                v4f A1 = cp[top + 17], B1 = cp[top + 18], C1 = cp[top + 19];
                v4f A2 = cp[top + 34], B2 = cp[top + 35], C2 = cp[top + 36];
                // px0 (center B1; rows w0,w1,w2)
                pk4(p0[0], B1, A0); pk4(p0[1], B1, B0); pk4(p0[2], B1, C0);
                pk4(p0[3], B1, A1); pk4(p0[4], B1, C1);
                pk4(p0[5], B1, A2); pk4(s01,   B1, B2); pk4(p0[7], B1, C2);
                // row3 -> slot0
                A0 = cp[top + 51]; B0 = cp[top + 52]; C0 = cp[top + 53];
                // px1 (center B2; rows w1,w2,w3)
                pk4(p1[0], B2, A1); pk4(p1[2], B2, C1);
                pk4(p1[3], B2, A2); pk4(p1[4], B2, C2);
                pk4(p1[5], B2, A0); pk4(s12,   B2, B0); pk4(p1[7], B2, C0);
                // row4 -> slot1
                A1 = cp[top + 68]; B1 = cp[top + 69]; C1 = cp[top + 70];
                // px2 (center B0=row3; rows w2,w3,w4)
                pk4(p2[0], B0, A2); pk4(p2[2], B0, C2);
                pk4(p2[3], B0, A0); pk4(p2[4], B0, C0);
                pk4(p2[5], B0, A1); pk4(s23,   B0, B1); pk4(p2[7], B0, C1);
                // row5 -> slot2
                A2 = cp[top + 85]; B2 = cp[top + 86]; C2 = cp[top + 87];
                // px3 (center B1=row4; rows w3,w4,w5)
                pk4(p3[0], B1, A0); pk4(p3[2], B1, C0);
                pk4(p3[3], B1, A1); pk4(p3[4], B1, C1);
                pk4(p3[5], B1, A2); pk4(p3[6], B1, B2); pk4(p3[7], B1, C2);
            }
        }

        if (more) {
            const int nb = (t + 1) & 1;
            #pragma unroll
            for (int g = 0; g < GRP; ++g) {
                float a0 = pv[4 * g + 0], a1 = pv[4 * g + 1];
                float a2 = pv[4 * g + 2], a3 = pv[4 * g + 3];
                ss0 += a0 * a0 + a1 * a1 + a2 * a2 + a3 * a3;
                v4f v = {a0, a1, a2, a3};
                tiles[half][nb][g][spad] = v;
            }
            __syncthreads();
        }
    }

    // ---- publish norms + cross-half dot partials
    ssp[half][t8] = ss0;
    if (is_q) {
        if (half == 1) {
            float* d = exA[t8];
            d[0]=p0[0].x+p0[0].y; d[1]=p0[1].x+p0[1].y; d[2]=p0[2].x+p0[2].y;
            d[3]=p0[3].x+p0[3].y; d[4]=p0[4].x+p0[4].y; d[5]=p0[5].x+p0[5].y;
            d[6]=s01.x+s01.y;     d[7]=p0[7].x+p0[7].y;
            d[8]=p1[0].x+p1[0].y; d[9]=s01.x+s01.y;     d[10]=p1[2].x+p1[2].y;
            d[11]=p1[3].x+p1[3].y; d[12]=p1[4].x+p1[4].y; d[13]=p1[5].x+p1[5].y;
            d[14]=s12.x+s12.y;    d[15]=p1[7].x+p1[7].y;
        } else {
            float* d = exB[t8];
            d[0]=p2[0].x+p2[0].y; d[1]=s12.x+s12.y;     d[2]=p2[2].x+p2[2].y;
            d[3]=p2[3].x+p2[3].y; d[4]=p2[4].x+p2[4].y; d[5]=p2[5].x+p2[5].y;
            d[6]=s23.x+s23.y;     d[7]=p2[7].x+p2[7].y;
            d[8]=p3[0].x+p3[0].y; d[9]=s23.x+s23.y;     d[10]=p3[2].x+p3[2].y;
            d[11]=p3[3].x+p3[3].y; d[12]=p3[4].x+p3[4].y; d[13]=p3[5].x+p3[5].y;
            d[14]=p3[6].x+p3[6].y; d[15]=p3[7].x+p3[7].y;
        }
    }
    __syncthreads();
    if (tid < TILE_E)
        ssbuf[tid] = 1.0f / fmaxf(sqrtf(ssp[0][tid] + ssp[1][tid]), 1e-12f);
    __syncthreads();

    float lp = 0.0f;
    if (is_q) {
        auto epi = [&](const float* s8, int ciu, int gi) -> float {
            const float ssq = ssp[0][ciu] + ssp[1][ciu];
            const float invc = ssbuf[ciu] * INV_T;
            const float l00 = s8[0] * invc * ssbuf[ciu - 16 - 1];
            const float l01 = s8[1] * invc * ssbuf[ciu - 16];
            const float l02 = s8[2] * invc * ssbuf[ciu - 16 + 1];
            const float l10 = s8[3] * invc * ssbuf[ciu - 1];
            const float l11 = ssq  * invc * ssbuf[ciu];
            const float l12 = s8[4] * invc * ssbuf[ciu + 1];
            const float l20 = s8[5] * invc * ssbuf[ciu + 16 - 1];
            const float l21 = s8[6] * invc * ssbuf[ciu + 16];
            const float l22 = s8[7] * invc * ssbuf[ciu + 16 + 1];

            const int pix = gi * W_ + gj;
            float denom = 0.f, sumlog = 0.f;
            #pragma unroll
            for (int m = 0; m < N_; ++m) {
                int d0 = dirs[((m * 2 + 0) * H_ + gi) * W_ + gj];
                int d1 = dirs[((m * 2 + 1) * H_ + gi) * W_ + gj];
                float q0 = sel3(d1, l00, l01, l02);
                float q1 = sel3(d1, l10, l11, l12);
                float q2 = sel3(d1, l20, l21, l22);
                float lm = sel3(d0, q0, q1, q2);
                int labm = labels[m * HW + pix];
                int labn = labels[n * HW + (gi + d0) * W_ + (gj + d1)];
                bool msk = (labm == labn);
                float e = msk ? __expf(lm) : 0.f;
                denom += e;
                sumlog += msk ? lm : -INFINITY;
            }
            return 8.0f * __logf(denom + 1e-6f) - sumlog;
        };

        if (half == 0) {
            if (qy < 3) {   // own px0,px1 (qy==3's rows 10,11 are dups)
                float f[8];
                const float* e = exA[t8];
                f[0]=p0[0].x+p0[0].y+e[0]; f[1]=p0[1].x+p0[1].y+e[1];
                f[2]=p0[2].x+p0[2].y+e[2]; f[3]=p0[3].x+p0[3].y+e[3];
                f[4]=p0[4].x+p0[4].y+e[4]; f[5]=p0[5].x+p0[5].y+e[5];
                f[6]=s01.x+s01.y+e[6];     f[7]=p0[7].x+p0[7].y+e[7];
                lp += epi(f, (b + 1) * 16 + tx + 1, gy0 + b);
                f[0]=p1[0].x+p1[0].y+e[8];  f[1]=s01.x+s01.y+e[9];
                f[2]=p1[2].x+p1[2].y+e[10]; f[3]=p1[3].x+p1[3].y+e[11];
                f[4]=p1[4].x+p1[4].y+e[12]; f[5]=p1[5].x+p1[5].y+e[13];
                f[6]=s12.x+s12.y+e[14];     f[7]=p1[7].x+p1[7].y+e[15];
                lp += epi(f, (b + 2) * 16 + tx + 1, gy0 + b + 1);
            }
        } else {            // own px2,px3 (all qy)
            float f[8];
            const float* e = exB[t8];
            f[0]=p2[0].x+p2[0].y+e[0]; f[1]=s12.x+s12.y+e[1];
            f[2]=p2[2].x+p2[2].y+e[2]; f[3]=p2[3].x+p2[3].y+e[3];
            f[4]=p2[4].x+p2[4].y+e[4]; f[5]=p2[5].x+p2[5].y+e[5];
            f[6]=s23.x+s23.y+e[6];     f[7]=p2[7].x+p2[7].y+e[7];
            lp += epi(f, (b + 3) * 16 + tx + 1, gy0 + b + 2);
            f[0]=p3[0].x+p3[0].y+e[8];  f[1]=s23.x+s23.y+e[9];
            f[2]=p3[2].x+p3[2].y+e[10]; f[3]=p3[3].x+p3[3].y+e[11];
            f[4]=p3[4].x+p3[4].y+e[12]; f[5]=p3[5].x+p3[5].y+e[13];
            f[6]=p3[6].x+p3[6].y+e[14]; f[7]=p3[7].x+p3[7].y+e[15];
            lp += epi(f, (b + 4) * 16 + tx + 1, gy0 + b + 3);
        }
    }

    // ---- block reduction (8 waves)
    #pragma unroll
    for (int off = 32; off > 0; off >>= 1) lp += __shfl_down(lp, off, 64);
    const int wave = tid >> 6, lane = tid & 63;
    if (lane == 0) red[wave] = lp;
    __syncthreads();
    if (tid == 0) {
        float tsum = 0.f;
        #pragma unroll
        for (int w = 0; w < NT / 64; ++w) tsum += red[w];
        if (use_partial) partial[bid] = (double)tsum;
        else atomicAdd(partial, (double)tsum);
    }
}

extern "C" __global__ void __launch_bounds__(256)
dcl_final(const double* __restrict__ partial, float* __restrict__ out, int nblk)
{
    const int tid = threadIdx.x;
    double s = 0.0;
    for (int i = tid; i < nblk; i += 256) s += partial[i];
    #pragma unroll
    for (int off = 32; off > 0; off >>= 1) s += __shfl_down(s, off, 64);
    __shared__ double red[4];
    const int lane = tid & 63, wv = tid >> 6;
    if (lane == 0) red[wv] = s;
    __syncthreads();
    if (tid == 0) out[0] = (float)((red[0] + red[1] + red[2] + red[3]) / TOTAL);
}

extern "C" void kernel_launch(void* const* d_in, const int* in_sizes, int n_in,
                              void* d_out, int out_size, void* d_ws, size_t ws_size,
                              hipStream_t stream) {
    const float* feat   = (const float*)d_in[0];
    const int*   labels = (const int*)d_in[1];
    const int*   dirs   = (const int*)d_in[2];
    double* acc = (double*)d_ws;
    float*  out = (float*)d_out;

    const int use_partial = (ws_size >= (size_t)NBLK * sizeof(double)) ? 1 : 0;
    if (!use_partial) hipMemsetAsync(acc, 0, sizeof(double), stream);
    dcl_main<<<dim3(NBLK), NT, 0, stream>>>(feat, labels, dirs, acc, use_partial);
    dcl_final<<<1, 256, 0, stream>>>(acc, out, use_partial ? NBLK : 1);
}

// Round 5
// 121.618 us; speedup vs baseline: 1.0228x; 1.0228x over previous
//
#include <hip/hip_runtime.h>
#include <math.h>

// DirectionalContrastiveLoss — N=8, C=192, H=W=112, T=0.1
//
// R10: R8's pair-blocking (known-good regs, no spills) with ONLY geometry +
// XCD mapping changed (R9 bundled 3 changes and regressed — likely spills).
//  - tile 7x28 px (+halo 9x30=270 slots): grid 512 blocks = exactly 2/CU
//    (cross-block overlap at every barrier; halo factor 1.38).
//  - XCD swizzle n=bid&7: image n's blocks all on XCD n -> per-chunk slab
//    (401KB) L2-resident -> halo re-reads are L2 hits; HBM -> ideal 77MB.
//  - pair blocking: 2 px/thread, pairs (0,1),(2,3),(4,5),(5,6) (row-5 dup
//    discarded); 112 pair threads/half; 15 v2f accs (s01 shared vertical
//    dot), ~100 VGPR -- safely under the 128 cap of launch_bounds(512,4).
//  - row stride padded to 31 v4f; KCH=8 double-buffered (12 barriers).
//  - epilogue split: half0 finishes px0 rows {0,2,4}, half1 px1 rows
//    {1,3,5,6}; partials exchanged via LDS.

namespace {
constexpr int N_ = 8, C_ = 192, H_ = 112, W_ = 112;
constexpr int HW = H_ * W_;
constexpr int TH = 7, WS = 28;         // pixel tile
constexpr int TROWS = 9, TCOLS = 30;   // +halo
constexpr int SPAD = 31;               // padded row stride (v4f units)
constexpr int TILE_E = TROWS * TCOLS;  // 270 staging slots
constexpr int NT2 = 256;               // threads per channel-half
constexpr int NT = 2 * NT2;            // 512
constexpr int EXTRA = TILE_E - NT2;    // 14 threads own a 2nd slot
constexpr int NPR = 4 * WS;            // 112 pair threads per half
constexpr int CHALF = C_ / 2;          // 96
constexpr int KCH = 8;                 // channels per chunk per half
constexpr int GRP = KCH / 4;           // 2 float4 groups
constexpr int NCHUNK = CHALF / KCH;    // 12
constexpr int NBLK = (W_ / WS) * (H_ / TH) * N_;  // 4*16*8 = 512
constexpr float INV_T = 10.0f;
constexpr double TOTAL = (double)N_ * N_ * H_ * W_;  // 802816
}

typedef float v2f __attribute__((ext_vector_type(2)));
typedef float v4f __attribute__((ext_vector_type(4)));

__device__ __forceinline__ void pk(v2f& a, v2f x, v2f y) {
    asm("v_pk_fma_f32 %0, %1, %2, %0" : "+v"(a) : "v"(x), "v"(y));
}
__device__ __forceinline__ void pk4(v2f& a, v4f x, v4f y) {
    pk(a, x.lo, y.lo); pk(a, x.hi, y.hi);
}

__device__ __forceinline__ float sel3(int d, float a, float b, float c) {
    float r = (d < 0) ? a : b;
    return (d > 0) ? c : r;
}

extern "C" __global__ void __launch_bounds__(NT, 4)
dcl_main(const float* __restrict__ feat,
         const int* __restrict__ labels,
         const int* __restrict__ dirs,
         double* __restrict__ partial, int use_partial)
{
    __shared__ v4f   tiles[2][2][GRP][TROWS * SPAD];  // 34.9 KB
    __shared__ float ssp[2][TILE_E];                  // 2.16 KB
    __shared__ float ssbuf[TILE_E];                   // 1.08 KB
    __shared__ float exA[NPR][9];                     // half1's px0 partials
    __shared__ float exB[NPR][9];                     // half0's px1 partials
    __shared__ float red[NT / 64];

    const int bid = blockIdx.x;
    const int n   = bid & 7;            // XCD swizzle: image n -> XCD n
    const int tt  = bid >> 3;           // 0..63
    const int tyb = tt >> 2;            // 0..15
    const int txb = tt & 3;             // 0..3
    const int gy0 = tyb * TH;
    const int gx0 = txb * WS;

    const int tid  = threadIdx.x;
    const int half = tid >> 8;
    const int t8   = tid & (NT2 - 1);

    // ---- staging slots -> clamped global offsets + padded LDS index
    int gofs0, gofs1 = 0, spad0, spad1 = 0;
    {
        int sr = t8 / TCOLS, sc = t8 - sr * TCOLS;
        spad0 = sr * SPAD + sc;
        gofs0 = min(max(gy0 + sr - 1, 0), H_ - 1) * W_
              + min(max(gx0 + sc - 1, 0), W_ - 1);
        if (t8 < EXTRA) {
            int s2 = t8 + NT2;
            sr = s2 / TCOLS; sc = s2 - sr * TCOLS;
            spad1 = sr * SPAD + sc;
            gofs1 = min(max(gy0 + sr - 1, 0), H_ - 1) * W_
                  + min(max(gx0 + sc - 1, 0), W_ - 1);
        }
    }

    // ---- pair mapping
    const bool is_p = (t8 < NPR);
    const int pr = t8 / WS;               // 0..3
    const int tx = t8 - pr * WS;          // 0..27
    const int r0 = (pr == 3) ? 5 : 2 * pr;   // px0 image row in tile
    const bool px0v = (pr < 3);              // pr3's px0 (row 5) is a dup
    const int top = r0 * SPAD + tx;       // window upper-left (v4f idx)
    const int gj  = gx0 + tx;

    const float* __restrict__ plane =
        feat + ((size_t)n * C_ + (size_t)half * CHALF) * HW;

    float ss0 = 0.0f, ss1 = 0.0f;

    // ---- prologue: stage chunk 0 into buffer 0
    {
        #pragma unroll
        for (int g = 0; g < GRP; ++g) {
            float a0 = plane[(size_t)(4 * g + 0) * HW + gofs0];
            float a1 = plane[(size_t)(4 * g + 1) * HW + gofs0];
            float a2 = plane[(size_t)(4 * g + 2) * HW + gofs0];
            float a3 = plane[(size_t)(4 * g + 3) * HW + gofs0];
            ss0 += a0 * a0 + a1 * a1 + a2 * a2 + a3 * a3;
            v4f v = {a0, a1, a2, a3};
            tiles[half][0][g][spad0] = v;
        }
        if (t8 < EXTRA) {
            #pragma unroll
            for (int g = 0; g < GRP; ++g) {
                float a0 = plane[(size_t)(4 * g + 0) * HW + gofs1];
                float a1 = plane[(size_t)(4 * g + 1) * HW + gofs1];
                float a2 = plane[(size_t)(4 * g + 2) * HW + gofs1];
                float a3 = plane[(size_t)(4 * g + 3) * HW + gofs1];
                ss1 += a0 * a0 + a1 * a1 + a2 * a2 + a3 * a3;
                v4f v = {a0, a1, a2, a3};
                tiles[half][0][g][spad1] = v;
            }
        }
    }
    __syncthreads();

    // accumulators: 15 v2f. q0 = px0's 7 own dirs, q1 = px1's 7, s01 shared
    // q0: [0]=(-1,-1) [1]=(-1,0) [2]=(-1,1) [3]=(0,-1) [4]=(0,1) [5]=(1,-1) [6]=(1,1)
    // q1: [0]=(-1,-1) [1]=(-1,1) [2]=(0,-1) [3]=(0,1) [4]=(1,-1) [5]=(1,0) [6]=(1,1)
    v2f q0[7], q1[7], s01;
    {
        const v2f z = {0.f, 0.f};
        #pragma unroll
        for (int d = 0; d < 7; ++d) { q0[d] = z; q1[d] = z; }
        s01 = z;
    }

    // ---- chunk loop: 1 barrier per 8 channels per half, double-buffered
    for (int t = 0; t < NCHUNK; ++t) {
        float pv0[KCH], pv1[KCH];
        const bool more = (t + 1 < NCHUNK);
        if (more) {
            const float* p = plane + (size_t)(t + 1) * KCH * HW;
            #pragma unroll
            for (int k = 0; k < KCH; ++k) pv0[k] = p[(size_t)k * HW + gofs0];
            if (t8 < EXTRA) {
                #pragma unroll
                for (int k = 0; k < KCH; ++k) pv1[k] = p[(size_t)k * HW + gofs1];
            }
        }

        if (is_p) {
            #pragma unroll
            for (int g = 0; g < GRP; ++g) {
                const v4f* __restrict__ cp = tiles[half][t & 1][g];
                v4f A0 = cp[top +  0], B0 = cp[top +  1], C0 = cp[top +  2];
                v4f A1 = cp[top + 31], B1 = cp[top + 32], C1 = cp[top + 33];
                v4f A2 = cp[top + 62], B2 = cp[top + 63], C2 = cp[top + 64];
                // px0 (center B1; rows r0,r0+1,r0+2)
                pk4(q0[0], B1, A0); pk4(q0[1], B1, B0); pk4(q0[2], B1, C0);
                pk4(q0[3], B1, A1); pk4(q0[4], B1, C1);
                pk4(q0[5], B1, A2); pk4(s01,   B1, B2); pk4(q0[6], B1, C2);
                v4f A3 = cp[top + 93], B3 = cp[top + 94], C3 = cp[top + 95];
                // px1 (center B2; rows r0+1,r0+2,r0+3); (-1,0) = s01
                pk4(q1[0], B2, A1); pk4(q1[1], B2, C1);
                pk4(q1[2], B2, A2); pk4(q1[3], B2, C2);
                pk4(q1[4], B2, A3); pk4(q1[5], B2, B3); pk4(q1[6], B2, C3);
            }
        }

        if (more) {
            const int nb = (t + 1) & 1;
            #pragma unroll
            for (int g = 0; g < GRP; ++g) {
                float a0 = pv0[4 * g + 0], a1 = pv0[4 * g + 1];
                float a2 = pv0[4 * g + 2], a3 = pv0[4 * g + 3];
                ss0 += a0 * a0 + a1 * a1 + a2 * a2 + a3 * a3;
                v4f v = {a0, a1, a2, a3};
                tiles[half][nb][g][spad0] = v;
            }
            if (t8 < EXTRA) {
                #pragma unroll
                for (int g = 0; g < GRP; ++g) {
                    float a0 = pv1[4 * g + 0], a1 = pv1[4 * g + 1];
                    float a2 = pv1[4 * g + 2], a3 = pv1[4 * g + 3];
                    ss1 += a0 * a0 + a1 * a1 + a2 * a2 + a3 * a3;
                    v4f v = {a0, a1, a2, a3};
                    tiles[half][nb][g][spad1] = v;
                }
            }
            __syncthreads();
        }
    }

    // ---- publish norm partials + cross-half dot partials
    ssp[half][t8] = ss0;
    if (t8 < EXTRA) ssp[half][t8 + NT2] = ss1;
    if (is_p) {
        if (half == 1) {   // send px0 partials (order 00,01,02,10,12,20,21,22)
            float* d = exA[t8];
            d[0]=q0[0].x+q0[0].y; d[1]=q0[1].x+q0[1].y; d[2]=q0[2].x+q0[2].y;
            d[3]=q0[3].x+q0[3].y; d[4]=q0[4].x+q0[4].y; d[5]=q0[5].x+q0[5].y;
            d[6]=s01.x+s01.y;     d[7]=q0[6].x+q0[6].y;
        } else {           // send px1 partials
            float* d = exB[t8];
            d[0]=q1[0].x+q1[0].y; d[1]=s01.x+s01.y;     d[2]=q1[1].x+q1[1].y;
            d[3]=q1[2].x+q1[2].y; d[4]=q1[3].x+q1[3].y; d[5]=q1[4].x+q1[4].y;
            d[6]=q1[5].x+q1[5].y; d[7]=q1[6].x+q1[6].y;
        }
    }
    __syncthreads();
    if (tid < TILE_E)
        ssbuf[tid] = 1.0f / fmaxf(sqrtf(ssp[0][tid] + ssp[1][tid]), 1e-12f);
    __syncthreads();

    float lp = 0.0f;
    if (is_p) {
        auto epi = [&](const float* s8, int ciu, int gi) -> float {
            const float ssq = ssp[0][ciu] + ssp[1][ciu];
            const float invc = ssbuf[ciu] * INV_T;
            const float l00 = s8[0] * invc * ssbuf[ciu - TCOLS - 1];
            const float l01 = s8[1] * invc * ssbuf[ciu - TCOLS];
            const float l02 = s8[2] * invc * ssbuf[ciu - TCOLS + 1];
            const float l10 = s8[3] * invc * ssbuf[ciu - 1];
            const float l11 = ssq  * invc * ssbuf[ciu];
            const float l12 = s8[4] * invc * ssbuf[ciu + 1];
            const float l20 = s8[5] * invc * ssbuf[ciu + TCOLS - 1];
            const float l21 = s8[6] * invc * ssbuf[ciu + TCOLS];
            const float l22 = s8[7] * invc * ssbuf[ciu + TCOLS + 1];

            const int pix = gi * W_ + gj;
            float denom = 0.f, sumlog = 0.f;
            #pragma unroll
            for (int m = 0; m < N_; ++m) {
                int d0 = dirs[((m * 2 + 0) * H_ + gi) * W_ + gj];
                int d1 = dirs[((m * 2 + 1) * H_ + gi) * W_ + gj];
                float e0 = sel3(d1, l00, l01, l02);
                float e1 = sel3(d1, l10, l11, l12);
                float e2 = sel3(d1, l20, l21, l22);
                float lm = sel3(d0, e0, e1, e2);
                int labm = labels[m * HW + pix];
                int labn = labels[n * HW + (gi + d0) * W_ + (gj + d1)];
                bool msk = (labm == labn);
                float e = msk ? __expf(lm) : 0.f;
                denom += e;
                sumlog += msk ? lm : -INFINITY;
            }
            return 8.0f * __logf(denom + 1e-6f) - sumlog;
        };

        if (half == 0) {
            if (px0v) {   // own px0: combine with half1's exA
                float f[8];
                const float* e = exA[t8];
                f[0]=q0[0].x+q0[0].y+e[0]; f[1]=q0[1].x+q0[1].y+e[1];
                f[2]=q0[2].x+q0[2].y+e[2]; f[3]=q0[3].x+q0[3].y+e[3];
                f[4]=q0[4].x+q0[4].y+e[4]; f[5]=q0[5].x+q0[5].y+e[5];
                f[6]=s01.x+s01.y+e[6];     f[7]=q0[6].x+q0[6].y+e[7];
                lp = epi(f, (r0 + 1) * TCOLS + tx + 1, gy0 + r0);
            }
        } else {          // own px1: combine with half0's exB
            float f[8];
            const float* e = exB[t8];
            f[0]=q1[0].x+q1[0].y+e[0]; f[1]=s01.x+s01.y+e[1];
            f[2]=q1[1].x+q1[1].y+e[2]; f[3]=q1[2].x+q1[2].y+e[3];
            f[4]=q1[3].x+q1[3].y+e[4]; f[5]=q1[4].x+q1[4].y+e[5];
            f[6]=q1[5].x+q1[5].y+e[6]; f[7]=q1[6].x+q1[6].y+e[7];
            lp = epi(f, (r0 + 2) * TCOLS + tx + 1, gy0 + r0 + 1);
        }
    }

    // ---- block reduction (8 waves)
    #pragma unroll
    for (int off = 32; off > 0; off >>= 1) lp += __shfl_down(lp, off, 64);
    const int wave = tid >> 6, lane = tid & 63;
    if (lane == 0) red[wave] = lp;
    __syncthreads();
    if (tid == 0) {
        float tsum = 0.f;
        #pragma unroll
        for (int w = 0; w < NT / 64; ++w) tsum += red[w];
        if (use_partial) partial[bid] = (double)tsum;
        else atomicAdd(partial, (double)tsum);
    }
}

extern "C" __global__ void __launch_bounds__(256)
dcl_final(const double* __restrict__ partial, float* __restrict__ out, int nblk)
{
    const int tid = threadIdx.x;
    double s = 0.0;
    for (int i = tid; i < nblk; i += 256) s += partial[i];
    #pragma unroll
    for (int off = 32; off > 0; off >>= 1) s += __shfl_down(s, off, 64);
    __shared__ double red[4];
    const int lane = tid & 63, wv = tid >> 6;
    if (lane == 0) red[wv] = s;
    __syncthreads();
    if (tid == 0) out[0] = (float)((red[0] + red[1] + red[2] + red[3]) / TOTAL);
}

extern "C" void kernel_launch(void* const* d_in, const int* in_sizes, int n_in,
                              void* d_out, int out_size, void* d_ws, size_t ws_size,
                              hipStream_t stream) {
    const float* feat   = (const float*)d_in[0];
    const int*   labels = (const int*)d_in[1];
    const int*   dirs   = (const int*)d_in[2];
    double* acc = (double*)d_ws;
    float*  out = (float*)d_out;

    const int use_partial = (ws_size >= (size_t)NBLK * sizeof(double)) ? 1 : 0;
    if (!use_partial) hipMemsetAsync(acc, 0, sizeof(double), stream);
    dcl_main<<<dim3(NBLK), NT, 0, stream>>>(feat, labels, dirs, acc, use_partial);
    dcl_final<<<1, 256, 0, stream>>>(acc, out, use_partial ? NBLK : 1);
}